// Round 5
// baseline (41.153 us; speedup 1.0000x reference)
//
#include <hip/hip_runtime.h>

#define EPSF 1e-7f
#define SCALEF (1.0f / 7.0f)

__device__ __forceinline__ float pair_iou(const float* b1, const float* b2) {
    float b1x1 = b1[0] - b1[2] * 0.5f, b1x2 = b1[0] + b1[2] * 0.5f;
    float b1y1 = b1[1] - b1[3] * 0.5f, b1y2 = b1[1] + b1[3] * 0.5f;
    float b2x1 = b2[0] - b2[2] * 0.5f, b2x2 = b2[0] + b2[2] * 0.5f;
    float b2y1 = b2[1] - b2[3] * 0.5f, b2y2 = b2[1] + b2[3] * 0.5f;
    float iw = fmaxf(fminf(b1x2, b2x2) - fmaxf(b1x1, b2x1), 0.0f);
    float ih = fmaxf(fminf(b1y2, b2y2) - fmaxf(b1y1, b2y1), 0.0f);
    float inter = iw * ih + EPSF;
    float w1 = b1x2 - b1x1, h1 = b1y2 - b1y1 + EPSF;
    float w2 = b2x2 - b2x1, h2 = b2y2 - b2y1 + EPSF;
    float uni = w1 * h1 + w2 * h2 - inter + EPSF;
    return inter / uni;
}

// Direct global->LDS DMA (16B/lane), wave-uniform base + lane*16 (linear dest).
__device__ __forceinline__ void gload_lds16(const float4* g, float4* l) {
    __builtin_amdgcn_global_load_lds(
        (const __attribute__((address_space(1))) unsigned int*)g,
        (__attribute__((address_space(3))) unsigned int*)l,
        16, 0, 0);
}

// ONE chunk per block: 128 cells, 256 threads, 6272 blocks (5 blocks/CU).
// stage (global_load_lds) -> sync -> compute (waves 0-1 box, waves 2-3 class)
// -> wave reduce -> partial. Cross-phase overlap comes from 5 independent
// blocks/CU instead of a serialized in-block chunk loop (round-5 change).
__global__ __launch_bounds__(256) void yolo_loss_partial(
        const float* __restrict__ pre, const float* __restrict__ targ,
        float* __restrict__ partial) {
    __shared__ float4 s4[1920];                      // [0,960) = pre, [960,1920) = targ
    float* sp = reinterpret_cast<float*>(s4);
    float* st = reinterpret_cast<float*>(s4 + 960);
    const int tid = threadIdx.x;
    const int wid = tid >> 6;

    const size_t base = (size_t)blockIdx.x * 128 * 30;
    const float4* gp = reinterpret_cast<const float4*>(pre + base);
    const float4* gt = reinterpret_cast<const float4*>(targ + base);
    float4* sp4 = s4;
    float4* st4 = s4 + 960;
#pragma unroll
    for (int k = 0; k < 3; ++k) {                    // 768 of 960 float4 per array
        int idx = tid + 256 * k;
        gload_lds16(gp + idx, sp4 + (wid * 64 + 256 * k));
        gload_lds16(gt + idx, st4 + (wid * 64 + 256 * k));
    }
    if (tid < 192) {                                 // tail 768..959 (waves 0-2, uniform)
        int idx = tid + 768;
        gload_lds16(gp + idx, sp4 + (wid * 64 + 768));
        gload_lds16(gt + idx, st4 + (wid * 64 + 768));
    }
    __syncthreads();                                 // drains vmcnt -> LDS valid

    const int half = tid >> 7;                       // wave-uniform: 0-1 box, 2-3 class
    const int c = tid & 127;
    const float* cp = sp + c * 30;
    const float* ct = st + c * 30;
    float acc = 0.0f;
    if (half == 0) {
        float p[10], t[10];
        const float2* cp2 = reinterpret_cast<const float2*>(cp);
        const float2* ct2 = reinterpret_cast<const float2*>(ct);
#pragma unroll
        for (int i = 0; i < 5; ++i) {
            float2 a = cp2[i]; p[2 * i] = a.x; p[2 * i + 1] = a.y;
            float2 b = ct2[i]; t[2 * i] = b.x; t[2 * i + 1] = b.y;
        }
        bool cell_obj   = t[4] > 0.0f;
        bool cell_noobj = t[4] == 0.0f;
        float iou0 = pair_iou(p + 0, t + 0);
        float iou1 = pair_iou(p + 5, t + 5);
        int resp    = (iou1 > iou0) ? 1 : 0;         // jnp.argmax first-index semantics
        int nonresp = (iou1 < iou0) ? 1 : 0;
        float xnr = nonresp ? t[5] : t[0];
        float ynr = nonresp ? t[6] : t[1];
        float fx = (xnr - (ceilf(xnr / SCALEF) - 1.0f) * SCALEF) / SCALEF;
        float fy = (ynr - (ceilf(ynr / SCALEF) - 1.0f) * SCALEF) / SCALEF;
        float lxy = 0.0f, lwh = 0.0f, lconf = 0.0f, lnoconf = 0.0f;
#pragma unroll
        for (int i = 0; i < 2; ++i) {
            const float* pb = p + i * 5;
            const float* tb = t + i * 5;
            bool is_resp    = (i == resp);
            bool is_nonresp = (i == nonresp);
            float new_conf = is_nonresp ? 0.0f : tb[4];
            if (cell_obj) {
                if (is_resp) {
                    float dx = pb[0] - fx, dy = pb[1] - fy;
                    lxy += dx * dx + dy * dy;
                    float dw = sqrtf(pb[2] + EPSF) - sqrtf(tb[2] + EPSF);
                    float dh = sqrtf(pb[3] + EPSF) - sqrtf(tb[3] + EPSF);
                    lwh += dw * dw + dh * dh;
                    float dc = pb[4] - new_conf;
                    lconf += dc * dc;
                } else {
                    float dc = pb[4] - new_conf;
                    lnoconf += dc * dc;
                }
            }
            if (cell_noobj) {
                float dc = pb[4] - tb[4];
                lnoconf += dc * dc;
            }
        }
        acc = 5.0f * (lxy + lwh) + lconf + 0.5f * lnoconf;
    } else {
        float tobj = ct[4];
        if (tobj > 0.0f) {
            float s = 0.0f;
            const float2* cp2 = reinterpret_cast<const float2*>(cp + 10);
            const float2* ct2 = reinterpret_cast<const float2*>(ct + 10);
#pragma unroll
            for (int i = 0; i < 10; ++i) {
                float2 a = cp2[i], b = ct2[i];
                float d0 = a.x - b.x, d1 = a.y - b.y;
                s += d0 * d0 + d1 * d1;
            }
            acc = s;
        }
    }

    // wave64 shuffle reduce, then cross-wave via LDS
#pragma unroll
    for (int off = 32; off > 0; off >>= 1) acc += __shfl_down(acc, off, 64);
    __shared__ float ssum[4];
    int lane = tid & 63;
    if (lane == 0) ssum[wid] = acc;
    __syncthreads();
    if (tid == 0) partial[blockIdx.x] = ssum[0] + ssum[1] + ssum[2] + ssum[3];
}

__global__ __launch_bounds__(256) void yolo_loss_final(
        const float* __restrict__ partial, int n, float invB, float* __restrict__ out) {
    float v = 0.0f;
    for (int i = threadIdx.x; i < n; i += 256) v += partial[i];
#pragma unroll
    for (int off = 32; off > 0; off >>= 1) v += __shfl_down(v, off, 64);
    __shared__ float ssum[4];
    int lane = threadIdx.x & 63, wid = threadIdx.x >> 6;
    if (lane == 0) ssum[wid] = v;
    __syncthreads();
    if (threadIdx.x == 0) out[0] = (ssum[0] + ssum[1] + ssum[2] + ssum[3]) * invB;
}

extern "C" void kernel_launch(void* const* d_in, const int* in_sizes, int n_in,
                              void* d_out, int out_size, void* d_ws, size_t ws_size,
                              hipStream_t stream) {
    const float* pre  = (const float*)d_in[0];
    const float* targ = (const float*)d_in[1];
    float* out = (float*)d_out;
    float* partial = (float*)d_ws;

    int B = in_sizes[0] / 1470;            // 16384
    int n_cells = B * 49;                  // 802816 = 6272 * 128 exactly
    int nblocks = n_cells / 128;           // 6272

    yolo_loss_partial<<<nblocks, 256, 0, stream>>>(pre, targ, partial);
    yolo_loss_final<<<1, 256, 0, stream>>>(partial, nblocks, 1.0f / (float)B, out);
}

// Round 6
// 39.536 us; speedup vs baseline: 1.0409x; 1.0409x over previous
//
#include <hip/hip_runtime.h>

#define EPSF 1e-7f
#define SCALEF (1.0f / 7.0f)

__device__ __forceinline__ float pair_iou(const float* b1, const float* b2) {
    float b1x1 = b1[0] - b1[2] * 0.5f, b1x2 = b1[0] + b1[2] * 0.5f;
    float b1y1 = b1[1] - b1[3] * 0.5f, b1y2 = b1[1] + b1[3] * 0.5f;
    float b2x1 = b2[0] - b2[2] * 0.5f, b2x2 = b2[0] + b2[2] * 0.5f;
    float b2y1 = b2[1] - b2[3] * 0.5f, b2y2 = b2[1] + b2[3] * 0.5f;
    float iw = fmaxf(fminf(b1x2, b2x2) - fmaxf(b1x1, b2x1), 0.0f);
    float ih = fmaxf(fminf(b1y2, b2y2) - fmaxf(b1y1, b2y1), 0.0f);
    float inter = iw * ih + EPSF;
    float w1 = b1x2 - b1x1, h1 = b1y2 - b1y1 + EPSF;
    float w2 = b2x2 - b2x1, h2 = b2y2 - b2y1 + EPSF;
    float uni = w1 * h1 + w2 * h2 - inter + EPSF;
    return inter / uni;
}

__device__ __forceinline__ void gload_lds16(const float4* g, float4* l) {
    __builtin_amdgcn_global_load_lds(
        (const __attribute__((address_space(1))) unsigned int*)g,
        (__attribute__((address_space(3))) unsigned int*)l,
        16, 0, 0);
}

// Stage one 64-cell chunk (480 f4 pre + 480 f4 targ) into buf.
// Every wave issues EXACTLY 4 vmem ops (wave 3 partially exec-masked on ops
// 2/4 but still issues) -> uniform per-wave vmcnt increment of 4.
__device__ __forceinline__ void stage_chunk(const float4* gp, const float4* gt,
                                            float4* buf, int tid, int wid) {
    gload_lds16(gp + tid,       buf + wid * 64);              // pre   0..255
    if (tid < 224)
        gload_lds16(gp + 256 + tid, buf + 256 + wid * 64);    // pre 256..479
    gload_lds16(gt + tid,       buf + 480 + wid * 64);        // targ  0..255
    if (tid < 224)
        gload_lds16(gt + 256 + tid, buf + 480 + 256 + wid * 64); // targ 256..479
}

// 256 threads, 8 chunks x 64 cells per block (1568 blocks), double-buffered
// in 30720B LDS (5 blocks/CU). Counted-vmcnt pipeline (T3/T4): issue next
// chunk's loads, s_waitcnt vmcnt(4) (previous chunk only), raw s_barrier,
// compute, raw s_barrier. No vmcnt(0) drain inside the loop.
__global__ __launch_bounds__(256) void yolo_loss_partial(
        const float* __restrict__ pre, const float* __restrict__ targ,
        float* __restrict__ partial) {
    __shared__ float4 s4[2][960];
    const int tid = threadIdx.x;
    const int wid = tid >> 6;
    const int lane = tid & 63;

    const size_t cell0 = (size_t)blockIdx.x * 512;            // 8 * 64 cells
    const float4* gp = reinterpret_cast<const float4*>(pre  + cell0 * 30);
    const float4* gt = reinterpret_cast<const float4*>(targ + cell0 * 30);
    float acc = 0.0f;

    stage_chunk(gp, gt, &s4[0][0], tid, wid);                 // prologue: chunk 0

#pragma unroll
    for (int c = 0; c < 8; ++c) {
        if (c < 7)
            stage_chunk(gp + (size_t)(c + 1) * 480, gt + (size_t)(c + 1) * 480,
                        &s4[(c + 1) & 1][0], tid, wid);
        if (c < 7) { asm volatile("s_waitcnt vmcnt(4)" ::: "memory"); }
        else       { asm volatile("s_waitcnt vmcnt(0)" ::: "memory"); }
        __builtin_amdgcn_s_barrier();                         // chunk c fully in LDS
        __builtin_amdgcn_sched_barrier(0);                    // rule #18: no hoisting

        const float* bufF = reinterpret_cast<const float*>(&s4[c & 1][0]);
        float loss = 0.0f;
        if (wid == 0) {
            // wave 0: box/conf terms for 64 cells (cell = lane)
            const float* cp = bufF + lane * 30;
            const float* ct = bufF + 1920 + lane * 30;
            float p[10], t[10];
            const float2* cp2 = reinterpret_cast<const float2*>(cp);
            const float2* ct2 = reinterpret_cast<const float2*>(ct);
#pragma unroll
            for (int i = 0; i < 5; ++i) {
                float2 a = cp2[i]; p[2 * i] = a.x; p[2 * i + 1] = a.y;
                float2 b = ct2[i]; t[2 * i] = b.x; t[2 * i + 1] = b.y;
            }
            bool cell_obj   = t[4] > 0.0f;
            bool cell_noobj = t[4] == 0.0f;
            float iou0 = pair_iou(p + 0, t + 0);
            float iou1 = pair_iou(p + 5, t + 5);
            int resp    = (iou1 > iou0) ? 1 : 0;              // jnp.argmax first-index
            int nonresp = (iou1 < iou0) ? 1 : 0;
            float xnr = nonresp ? t[5] : t[0];
            float ynr = nonresp ? t[6] : t[1];
            float fx = (xnr - (ceilf(xnr / SCALEF) - 1.0f) * SCALEF) / SCALEF;
            float fy = (ynr - (ceilf(ynr / SCALEF) - 1.0f) * SCALEF) / SCALEF;
            float lxy = 0.0f, lwh = 0.0f, lconf = 0.0f, lnoconf = 0.0f;
#pragma unroll
            for (int i = 0; i < 2; ++i) {
                const float* pb = p + i * 5;
                const float* tb = t + i * 5;
                bool is_resp    = (i == resp);
                bool is_nonresp = (i == nonresp);
                float new_conf = is_nonresp ? 0.0f : tb[4];
                if (cell_obj) {
                    if (is_resp) {
                        float dx = pb[0] - fx, dy = pb[1] - fy;
                        lxy += dx * dx + dy * dy;
                        float dw = sqrtf(pb[2] + EPSF) - sqrtf(tb[2] + EPSF);
                        float dh = sqrtf(pb[3] + EPSF) - sqrtf(tb[3] + EPSF);
                        lwh += dw * dw + dh * dh;
                        float dc = pb[4] - new_conf;
                        lconf += dc * dc;
                    } else {
                        float dc = pb[4] - new_conf;
                        lnoconf += dc * dc;
                    }
                }
                if (cell_noobj) {
                    float dc = pb[4] - tb[4];
                    lnoconf += dc * dc;
                }
            }
            loss = 5.0f * (lxy + lwh) + lconf + 0.5f * lnoconf;
        } else if (wid < 3) {
            // waves 1-2: class term, 2 lanes per cell, 10 floats each
            int q = tid - 64;                                  // 0..127
            int cc = q & 63, h = q >> 6;
            const float* ct = bufF + 1920 + cc * 30;
            if (ct[4] > 0.0f) {
                const float2* cp2 = reinterpret_cast<const float2*>(bufF + cc * 30 + 10 + h * 10);
                const float2* ct2 = reinterpret_cast<const float2*>(ct + 10 + h * 10);
                float s = 0.0f;
#pragma unroll
                for (int i = 0; i < 5; ++i) {
                    float2 a = cp2[i], b = ct2[i];
                    float d0 = a.x - b.x, d1 = a.y - b.y;
                    s += d0 * d0 + d1 * d1;
                }
                loss = s;
            }
        }
        acc += loss;
        if (c < 7) __builtin_amdgcn_s_barrier();              // buf[c&1] free before overwrite
    }

    // wave64 shuffle reduce, then cross-wave via LDS
#pragma unroll
    for (int off = 32; off > 0; off >>= 1) acc += __shfl_down(acc, off, 64);
    __shared__ float ssum[4];
    if (lane == 0) ssum[wid] = acc;
    __syncthreads();
    if (tid == 0) partial[blockIdx.x] = ssum[0] + ssum[1] + ssum[2] + ssum[3];
}

__global__ __launch_bounds__(256) void yolo_loss_final(
        const float* __restrict__ partial, int n, float invB, float* __restrict__ out) {
    float v = 0.0f;
    for (int i = threadIdx.x; i < n; i += 256) v += partial[i];
#pragma unroll
    for (int off = 32; off > 0; off >>= 1) v += __shfl_down(v, off, 64);
    __shared__ float ssum[4];
    int lane = threadIdx.x & 63, wid = threadIdx.x >> 6;
    if (lane == 0) ssum[wid] = v;
    __syncthreads();
    if (threadIdx.x == 0) out[0] = (ssum[0] + ssum[1] + ssum[2] + ssum[3]) * invB;
}

extern "C" void kernel_launch(void* const* d_in, const int* in_sizes, int n_in,
                              void* d_out, int out_size, void* d_ws, size_t ws_size,
                              hipStream_t stream) {
    const float* pre  = (const float*)d_in[0];
    const float* targ = (const float*)d_in[1];
    float* out = (float*)d_out;
    float* partial = (float*)d_ws;

    int B = in_sizes[0] / 1470;            // 16384
    int n_cells = B * 49;                  // 802816 = 1568 * 512 exactly
    int nblocks = n_cells / 512;           // 1568 blocks, 8 chunks each

    yolo_loss_partial<<<nblocks, 256, 0, stream>>>(pre, targ, partial);
    yolo_loss_final<<<1, 256, 0, stream>>>(partial, nblocks, 1.0f / (float)B, out);
}

// Round 7
// 38.643 us; speedup vs baseline: 1.0649x; 1.0231x over previous
//
#include <hip/hip_runtime.h>

#define EPSF 1e-7f
#define SCALEF (1.0f / 7.0f)

__device__ __forceinline__ float pair_iou(const float* b1, const float* b2) {
    float b1x1 = b1[0] - b1[2] * 0.5f, b1x2 = b1[0] + b1[2] * 0.5f;
    float b1y1 = b1[1] - b1[3] * 0.5f, b1y2 = b1[1] + b1[3] * 0.5f;
    float b2x1 = b2[0] - b2[2] * 0.5f, b2x2 = b2[0] + b2[2] * 0.5f;
    float b2y1 = b2[1] - b2[3] * 0.5f, b2y2 = b2[1] + b2[3] * 0.5f;
    float iw = fmaxf(fminf(b1x2, b2x2) - fmaxf(b1x1, b2x1), 0.0f);
    float ih = fmaxf(fminf(b1y2, b2y2) - fmaxf(b1y1, b2y1), 0.0f);
    float inter = iw * ih + EPSF;
    float w1 = b1x2 - b1x1, h1 = b1y2 - b1y1 + EPSF;
    float w2 = b2x2 - b2x1, h2 = b2y2 - b2y1 + EPSF;
    float uni = w1 * h1 + w2 * h2 - inter + EPSF;
    return inter / uni;
}

// R2-winning structure, but 512 threads/block for FULL wave occupancy:
// 8 waves x 4 blocks/CU = 32 waves/CU (vs 20 before). 3136 blocks, each
// 2 chunks x 128 cells, single 30720B LDS buffer, stage->sync->compute->sync.
// All 8 waves stage; compute: waves 0-1 box, 2-5 class (2 lanes/cell),
// 6-7 barrier-only (VALU is ~11% busy; idle compute lanes are free).
__global__ __launch_bounds__(512) void yolo_loss_partial(
        const float* __restrict__ pre, const float* __restrict__ targ,
        float* __restrict__ partial) {
    __shared__ float4 s4[1920];                      // [0,960) = pre, [960,1920) = targ
    float* spF = reinterpret_cast<float*>(s4);       // 128 cells x 30 floats
    float* stF = spF + 3840;
    const int tid = threadIdx.x;
    const int wid = tid >> 6;
    const int lane = tid & 63;
    float acc = 0.0f;

#pragma unroll
    for (int chunk = 0; chunk < 2; ++chunk) {
        const size_t base = ((size_t)blockIdx.x * 256 + chunk * 128) * 30;
        const float4* gp = reinterpret_cast<const float4*>(pre + base);
        const float4* gt = reinterpret_cast<const float4*>(targ + base);
        // 1920 float4 total over 512 threads: 3 full rounds + 384 tail
#pragma unroll
        for (int k = 0; k < 3; ++k) {
            int idx = tid + 512 * k;
            const float4* src = (idx < 960) ? (gp + idx) : (gt + (idx - 960));
            s4[idx] = *src;
        }
        {
            int idx = tid + 1536;                    // [1536,2048): valid when tid<384
            if (idx < 1920) s4[idx] = gt[idx - 960];
        }
        __syncthreads();

        float loss = 0.0f;
        if (wid < 2) {
            // waves 0-1: box/conf for cell c = tid (0..127)
            const float* cp = spF + tid * 30;
            const float* ct = stF + tid * 30;
            float p[10], t[10];
            const float2* cp2 = reinterpret_cast<const float2*>(cp);
            const float2* ct2 = reinterpret_cast<const float2*>(ct);
#pragma unroll
            for (int i = 0; i < 5; ++i) {
                float2 a = cp2[i]; p[2 * i] = a.x; p[2 * i + 1] = a.y;
                float2 b = ct2[i]; t[2 * i] = b.x; t[2 * i + 1] = b.y;
            }
            bool cell_obj   = t[4] > 0.0f;
            bool cell_noobj = t[4] == 0.0f;
            float iou0 = pair_iou(p + 0, t + 0);
            float iou1 = pair_iou(p + 5, t + 5);
            int resp    = (iou1 > iou0) ? 1 : 0;     // jnp.argmax first-index semantics
            int nonresp = (iou1 < iou0) ? 1 : 0;
            float xnr = nonresp ? t[5] : t[0];
            float ynr = nonresp ? t[6] : t[1];
            float fx = (xnr - (ceilf(xnr / SCALEF) - 1.0f) * SCALEF) / SCALEF;
            float fy = (ynr - (ceilf(ynr / SCALEF) - 1.0f) * SCALEF) / SCALEF;
            float lxy = 0.0f, lwh = 0.0f, lconf = 0.0f, lnoconf = 0.0f;
#pragma unroll
            for (int i = 0; i < 2; ++i) {
                const float* pb = p + i * 5;
                const float* tb = t + i * 5;
                bool is_resp    = (i == resp);
                bool is_nonresp = (i == nonresp);
                float new_conf = is_nonresp ? 0.0f : tb[4];
                if (cell_obj) {
                    if (is_resp) {
                        float dx = pb[0] - fx, dy = pb[1] - fy;
                        lxy += dx * dx + dy * dy;
                        float dw = sqrtf(pb[2] + EPSF) - sqrtf(tb[2] + EPSF);
                        float dh = sqrtf(pb[3] + EPSF) - sqrtf(tb[3] + EPSF);
                        lwh += dw * dw + dh * dh;
                        float dc = pb[4] - new_conf;
                        lconf += dc * dc;
                    } else {
                        float dc = pb[4] - new_conf;
                        lnoconf += dc * dc;
                    }
                }
                if (cell_noobj) {
                    float dc = pb[4] - tb[4];
                    lnoconf += dc * dc;
                }
            }
            loss = 5.0f * (lxy + lwh) + lconf + 0.5f * lnoconf;
        } else if (wid < 6) {
            // waves 2-5: class term, 2 lanes/cell, 10 floats each
            int q = tid - 128;                        // 0..255
            int cc = q >> 1, h = q & 1;
            const float* ct = stF + cc * 30;
            if (ct[4] > 0.0f) {
                const float2* cp2 = reinterpret_cast<const float2*>(spF + cc * 30 + 10 + h * 10);
                const float2* ct2 = reinterpret_cast<const float2*>(ct + 10 + h * 10);
                float s = 0.0f;
#pragma unroll
                for (int i = 0; i < 5; ++i) {
                    float2 a = cp2[i], b = ct2[i];
                    float d0 = a.x - b.x, d1 = a.y - b.y;
                    s += d0 * d0 + d1 * d1;
                }
                loss = s;
            }
        }
        acc += loss;
        __syncthreads();                             // LDS reuse by next chunk
    }

    // wave64 shuffle reduce, then cross-wave via LDS
#pragma unroll
    for (int off = 32; off > 0; off >>= 1) acc += __shfl_down(acc, off, 64);
    __shared__ float ssum[8];
    if (lane == 0) ssum[wid] = acc;
    __syncthreads();
    if (tid == 0) {
        float s = 0.0f;
#pragma unroll
        for (int w = 0; w < 8; ++w) s += ssum[w];
        partial[blockIdx.x] = s;
    }
}

__global__ __launch_bounds__(256) void yolo_loss_final(
        const float* __restrict__ partial, int n, float invB, float* __restrict__ out) {
    float v = 0.0f;
    for (int i = threadIdx.x; i < n; i += 256) v += partial[i];
#pragma unroll
    for (int off = 32; off > 0; off >>= 1) v += __shfl_down(v, off, 64);
    __shared__ float ssum[4];
    int lane = threadIdx.x & 63, wid = threadIdx.x >> 6;
    if (lane == 0) ssum[wid] = v;
    __syncthreads();
    if (threadIdx.x == 0) out[0] = (ssum[0] + ssum[1] + ssum[2] + ssum[3]) * invB;
}

extern "C" void kernel_launch(void* const* d_in, const int* in_sizes, int n_in,
                              void* d_out, int out_size, void* d_ws, size_t ws_size,
                              hipStream_t stream) {
    const float* pre  = (const float*)d_in[0];
    const float* targ = (const float*)d_in[1];
    float* out = (float*)d_out;
    float* partial = (float*)d_ws;

    int B = in_sizes[0] / 1470;            // 16384
    int n_cells = B * 49;                  // 802816 = 3136 * 256 exactly
    int nblocks = n_cells / 256;           // 3136 blocks, 2 chunks x 128 cells

    yolo_loss_partial<<<nblocks, 512, 0, stream>>>(pre, targ, partial);
    yolo_loss_final<<<1, 256, 0, stream>>>(partial, nblocks, 1.0f / (float)B, out);
}

// Round 8
// 38.298 us; speedup vs baseline: 1.0745x; 1.0090x over previous
//
#include <hip/hip_runtime.h>

#define EPSF 1e-7f
#define SCALEF (1.0f / 7.0f)

__device__ __forceinline__ float pair_iou(const float* b1, const float* b2) {
    float b1x1 = b1[0] - b1[2] * 0.5f, b1x2 = b1[0] + b1[2] * 0.5f;
    float b1y1 = b1[1] - b1[3] * 0.5f, b1y2 = b1[1] + b1[3] * 0.5f;
    float b2x1 = b2[0] - b2[2] * 0.5f, b2x2 = b2[0] + b2[2] * 0.5f;
    float b2y1 = b2[1] - b2[3] * 0.5f, b2y2 = b2[1] + b2[3] * 0.5f;
    float iw = fmaxf(fminf(b1x2, b2x2) - fmaxf(b1x1, b2x1), 0.0f);
    float ih = fmaxf(fminf(b1y2, b2y2) - fmaxf(b1y1, b2y1), 0.0f);
    float inter = iw * ih + EPSF;
    float w1 = b1x2 - b1x1, h1 = b1y2 - b1y1 + EPSF;
    float w2 = b2x2 - b2x1, h2 = b2y2 - b2y1 + EPSF;
    float uni = w1 * h1 + w2 * h2 - inter + EPSF;
    return inter / uni;
}

// Best-measured structure (round 2): 256 threads, 256 cells in 2 chunks of
// 128. Per chunk: coalesced float4 reg-staging of 128 cells x 30 floats x 2
// arrays into linear LDS (30720 B, 5 blocks/CU), then wave-uniform split:
// waves 0-1 box/conf (floats 0..9), waves 2-3 class (10..29, obj-gated).
// Matrix of alternatives measured (R4-R7): global_load_lds, 1-chunk/block,
// 8-chunk dbuf + counted vmcnt, 512-thread full occupancy — all land at the
// same ~5.8 TB/s effective (92% of the 6.29 TB/s copy ubench), L3-resident
// replays == HBM-cold speed -> memory-system wall, this variant is fastest.
__global__ __launch_bounds__(256) void yolo_loss_partial(
        const float* __restrict__ pre, const float* __restrict__ targ,
        float* __restrict__ partial) {
    __shared__ float4 s4[1920];                      // [0,960) = pre, [960,1920) = targ
    float* sp = reinterpret_cast<float*>(s4);
    float* st = reinterpret_cast<float*>(s4 + 960);
    const int tid = threadIdx.x;
    float acc = 0.0f;

#pragma unroll
    for (int chunk = 0; chunk < 2; ++chunk) {
        const size_t base = ((size_t)blockIdx.x * 256 + chunk * 128) * 30;
        const float4* gp = reinterpret_cast<const float4*>(pre + base);
        const float4* gt = reinterpret_cast<const float4*>(targ + base);
        float4* sp4 = s4;
        float4* st4 = s4 + 960;
#pragma unroll
        for (int k = 0; k < 3; ++k) {                // 960 float4 per array, 256 threads
            int idx = tid + 256 * k;
            sp4[idx] = gp[idx];
            st4[idx] = gt[idx];
        }
        {
            int idx = tid + 768;
            if (idx < 960) { sp4[idx] = gp[idx]; st4[idx] = gt[idx]; }
        }
        __syncthreads();

        const int half = tid >> 7;                   // wave-uniform: waves 0-1 box, 2-3 class
        const int c = tid & 127;
        const float* cp = sp + c * 30;
        const float* ct = st + c * 30;
        float loss = 0.0f;
        if (half == 0) {
            float p[10], t[10];
            const float2* cp2 = reinterpret_cast<const float2*>(cp);
            const float2* ct2 = reinterpret_cast<const float2*>(ct);
#pragma unroll
            for (int i = 0; i < 5; ++i) {
                float2 a = cp2[i]; p[2 * i] = a.x; p[2 * i + 1] = a.y;
                float2 b = ct2[i]; t[2 * i] = b.x; t[2 * i + 1] = b.y;
            }
            bool cell_obj   = t[4] > 0.0f;
            bool cell_noobj = t[4] == 0.0f;
            float iou0 = pair_iou(p + 0, t + 0);
            float iou1 = pair_iou(p + 5, t + 5);
            int resp    = (iou1 > iou0) ? 1 : 0;     // jnp.argmax first-index semantics
            int nonresp = (iou1 < iou0) ? 1 : 0;
            float xnr = nonresp ? t[5] : t[0];
            float ynr = nonresp ? t[6] : t[1];
            float fx = (xnr - (ceilf(xnr / SCALEF) - 1.0f) * SCALEF) / SCALEF;
            float fy = (ynr - (ceilf(ynr / SCALEF) - 1.0f) * SCALEF) / SCALEF;
            float lxy = 0.0f, lwh = 0.0f, lconf = 0.0f, lnoconf = 0.0f;
#pragma unroll
            for (int i = 0; i < 2; ++i) {
                const float* pb = p + i * 5;
                const float* tb = t + i * 5;
                bool is_resp    = (i == resp);
                bool is_nonresp = (i == nonresp);
                float new_conf = is_nonresp ? 0.0f : tb[4];
                if (cell_obj) {
                    if (is_resp) {
                        float dx = pb[0] - fx, dy = pb[1] - fy;
                        lxy += dx * dx + dy * dy;
                        float dw = sqrtf(pb[2] + EPSF) - sqrtf(tb[2] + EPSF);
                        float dh = sqrtf(pb[3] + EPSF) - sqrtf(tb[3] + EPSF);
                        lwh += dw * dw + dh * dh;
                        float dc = pb[4] - new_conf;
                        lconf += dc * dc;
                    } else {
                        float dc = pb[4] - new_conf;
                        lnoconf += dc * dc;
                    }
                }
                if (cell_noobj) {
                    float dc = pb[4] - tb[4];
                    lnoconf += dc * dc;
                }
            }
            loss = 5.0f * (lxy + lwh) + lconf + 0.5f * lnoconf;
        } else {
            float tobj = ct[4];
            if (tobj > 0.0f) {
                float s = 0.0f;
                const float2* cp2 = reinterpret_cast<const float2*>(cp + 10);
                const float2* ct2 = reinterpret_cast<const float2*>(ct + 10);
#pragma unroll
                for (int i = 0; i < 10; ++i) {
                    float2 a = cp2[i], b = ct2[i];
                    float d0 = a.x - b.x, d1 = a.y - b.y;
                    s += d0 * d0 + d1 * d1;
                }
                loss = s;
            }
        }
        acc += loss;
        __syncthreads();                             // protect LDS reuse by next chunk
    }

    // wave64 shuffle reduce, then cross-wave via LDS
#pragma unroll
    for (int off = 32; off > 0; off >>= 1) acc += __shfl_down(acc, off, 64);
    __shared__ float ssum[4];
    int lane = tid & 63, wid = tid >> 6;
    if (lane == 0) ssum[wid] = acc;
    __syncthreads();
    if (tid == 0) partial[blockIdx.x] = ssum[0] + ssum[1] + ssum[2] + ssum[3];
}

__global__ __launch_bounds__(256) void yolo_loss_final(
        const float* __restrict__ partial, int n, float invB, float* __restrict__ out) {
    float v = 0.0f;
    for (int i = threadIdx.x; i < n; i += 256) v += partial[i];
#pragma unroll
    for (int off = 32; off > 0; off >>= 1) v += __shfl_down(v, off, 64);
    __shared__ float ssum[4];
    int lane = threadIdx.x & 63, wid = threadIdx.x >> 6;
    if (lane == 0) ssum[wid] = v;
    __syncthreads();
    if (threadIdx.x == 0) out[0] = (ssum[0] + ssum[1] + ssum[2] + ssum[3]) * invB;
}

extern "C" void kernel_launch(void* const* d_in, const int* in_sizes, int n_in,
                              void* d_out, int out_size, void* d_ws, size_t ws_size,
                              hipStream_t stream) {
    const float* pre  = (const float*)d_in[0];
    const float* targ = (const float*)d_in[1];
    float* out = (float*)d_out;
    float* partial = (float*)d_ws;

    int B = in_sizes[0] / 1470;            // 16384
    int n_cells = B * 49;                  // 802816 = 3136 * 256 exactly
    int nblocks = n_cells / 256;           // 3136

    yolo_loss_partial<<<nblocks, 256, 0, stream>>>(pre, targ, partial);
    yolo_loss_final<<<1, 256, 0, stream>>>(partial, nblocks, 1.0f / (float)B, out);
}